// Round 14
// baseline (166.526 us; speedup 1.0000x reference)
//
#include <hip/hip_runtime.h>
#include <hip/hip_bf16.h>

#define NNODES 50000
#define NFEAT  128
#define NEDGES 600000
#define HID    256
#define HID2   128
#define LEAKY  0.01f

typedef __attribute__((ext_vector_type(8))) short short8;
typedef __attribute__((ext_vector_type(4))) float floatx4;

__device__ __forceinline__ void split_bf16(float x, unsigned short& hi, unsigned short& lo) {
  union { float f; unsigned u; } a; a.f = x;
  hi = (unsigned short)(a.u >> 16);
  union { float f; unsigned u; } h; h.u = (unsigned)hi << 16;
  union { float f; unsigned u; } r; r.f = x - h.f;
  lo = (unsigned short)(r.u >> 16);
}

__device__ __forceinline__ unsigned short bf16_rne(float x) {
  union { float f; unsigned u; } a; a.f = x;
  unsigned r = a.u + 0x7FFFu + ((a.u >> 16) & 1u);
  return (unsigned short)(r >> 16);
}

// RNE pack two fp32 -> u32 of 2 bf16 (a in low half) — emits cvt_pk.
__device__ __forceinline__ unsigned pack2_rne(float a, float b) {
  __hip_bfloat162 h = __float22bfloat162_rn(make_float2(a, b));
  unsigned u; __builtin_memcpy(&u, &h, 4); return u;
}

__device__ __forceinline__ float ubits2f(unsigned u) {
  union { unsigned u; float f; } c; c.u = u; return c.f;
}

// relu(P+Q) for a packed bf16 pair (b1 pre-folded into P), repacked RNE.
__device__ __forceinline__ unsigned fuse2(unsigned pw, unsigned qw) {
  const float a0 = ubits2f(pw << 16), a1 = ubits2f(pw & 0xFFFF0000u);
  const float c0 = ubits2f(qw << 16), c1 = ubits2f(qw & 0xFFFF0000u);
  return pack2_rne(fmaxf(a0 + c0, 0.f), fmaxf(a1 + c1, 0.f));
}

// ---------------------------------------------------------------------------
// pack_w: W2 -> single-plane RNE bf16 B-frag order; W1' -> hi/lo split planes.
// ---------------------------------------------------------------------------
__global__ __launch_bounds__(256) void pack_w(const float* __restrict__ W2,
                                              const float* __restrict__ W1,
                                              unsigned short* __restrict__ W2F,
                                              unsigned short* __restrict__ W1F) {
  const int gid = blockIdx.x * 256 + threadIdx.x;
  if (gid < 32768) {
    const int idx = gid;
    const int i  = idx & 7;
    const int l  = (idx >> 3) & 63;
    const int nf = (idx >> 9) & 7;
    const int ks = idx >> 12;
    const int k   = ks * 32 + (l >> 4) * 8 + i;
    const int col = nf * 16 + (l & 15);
    W2F[idx] = bf16_rne(W2[k * HID2 + col]);
  } else if (gid < 32768 + 65536) {
    const int idx = gid - 32768;
    const int i  = idx & 7;
    const int l  = (idx >> 3) & 63;
    const int nf = (idx >> 9) & 31;
    const int ks = idx >> 14;
    const int k = ks * 32 + (l >> 4) * 8 + i;
    const int n = nf * 16 + (l & 15);
    const float v = (n < 256) ? W1[k * HID + n] : W1[(128 + k) * HID + (n - 256)];
    unsigned short hi, lo;
    split_bf16(v, hi, lo);
    W1F[idx]         = hi;
    W1F[65536 + idx] = lo;
  }
}

// ---------------------------------------------------------------------------
// pq_mfma: Pb[n][0:256] = bf16_rne( x[n] @ W1'[:,0:256] + b1 )
//          Qb[n][0:256] = bf16_rne( x[n] @ W1'[:,256:512] )
// ---------------------------------------------------------------------------
__global__ __launch_bounds__(256) void pq_mfma(
    const float* __restrict__ x, const unsigned short* __restrict__ W1F,
    const float* __restrict__ b1,
    unsigned short* __restrict__ Pb, unsigned short* __restrict__ Qb) {
  const int bid   = blockIdx.x;
  const int nhalf = bid & 1;
  const int n0    = (bid >> 1) * 64;
  const int t     = threadIdx.x;

  __shared__ __align__(16) unsigned short sbuf[2][64 * 128];  // 32 KB
  unsigned short* xhi = sbuf[0];
  unsigned short* xlo = sbuf[1];

#pragma unroll
  for (int rep = 0; rep < 8; ++rep) {
    const int flat = rep * 1024 + t * 4;
    const int row = flat >> 7, f0 = flat & 127;
    float4 v = make_float4(0.f, 0.f, 0.f, 0.f);
    if (n0 + row < NNODES)
      v = *reinterpret_cast<const float4*>(&x[(size_t)(n0 + row) * NFEAT + f0]);
    unsigned short h[4], l[4];
    split_bf16(v.x, h[0], l[0]); split_bf16(v.y, h[1], l[1]);
    split_bf16(v.z, h[2], l[2]); split_bf16(v.w, h[3], l[3]);
    const unsigned bt = (unsigned)(row * 256) +
                        (((unsigned)(2 * f0)) ^ (((unsigned)(row & 7)) << 4));
    *reinterpret_cast<uint2*>(reinterpret_cast<char*>(xhi) + bt) =
        make_uint2((unsigned)h[0] | ((unsigned)h[1] << 16),
                   (unsigned)h[2] | ((unsigned)h[3] << 16));
    *reinterpret_cast<uint2*>(reinterpret_cast<char*>(xlo) + bt) =
        make_uint2((unsigned)l[0] | ((unsigned)l[1] << 16),
                   (unsigned)l[2] | ((unsigned)l[3] << 16));
  }
  __syncthreads();

  const int wid = t >> 6, lane = t & 63;
  const int rg = wid >> 1, cg = wid & 1;
  const int lr = lane & 15, kc = lane >> 4;

  floatx4 acc[2][8];
#pragma unroll
  for (int mf = 0; mf < 2; ++mf)
#pragma unroll
    for (int nf = 0; nf < 8; ++nf) acc[mf][nf] = (floatx4)0.f;

#pragma unroll
  for (int ks = 0; ks < 4; ++ks) {
    short8 ah[2], al[2];
#pragma unroll
    for (int mf = 0; mf < 2; ++mf) {
      const int row = rg * 32 + mf * 16 + lr;
      const unsigned bt = (unsigned)(row * 256) +
                          (((unsigned)(ks * 64 + kc * 16)) ^ (((unsigned)(row & 7)) << 4));
      ah[mf] = *reinterpret_cast<const short8*>(reinterpret_cast<const char*>(xhi) + bt);
      al[mf] = *reinterpret_cast<const short8*>(reinterpret_cast<const char*>(xlo) + bt);
    }
#pragma unroll
    for (int nf = 0; nf < 8; ++nf) {
      const int nfg = nhalf * 16 + cg * 8 + nf;
      const size_t off = ((size_t)(ks * 32 + nfg) * 64 + lane) * 8;
      const short8 bh = *reinterpret_cast<const short8*>(W1F + off);
      const short8 bl = *reinterpret_cast<const short8*>(W1F + 65536 + off);
#pragma unroll
      for (int mf = 0; mf < 2; ++mf) {
        acc[mf][nf] = __builtin_amdgcn_mfma_f32_16x16x32_bf16(ah[mf], bh, acc[mf][nf], 0, 0, 0);
        acc[mf][nf] = __builtin_amdgcn_mfma_f32_16x16x32_bf16(ah[mf], bl, acc[mf][nf], 0, 0, 0);
        acc[mf][nf] = __builtin_amdgcn_mfma_f32_16x16x32_bf16(al[mf], bh, acc[mf][nf], 0, 0, 0);
      }
    }
  }

  float bias[8];
#pragma unroll
  for (int nf = 0; nf < 8; ++nf)
    bias[nf] = (nhalf == 0) ? b1[cg * 128 + nf * 16 + lr] : 0.f;

  __syncthreads();
  unsigned short* stg = &sbuf[0][0];
#pragma unroll
  for (int mf = 0; mf < 2; ++mf)
#pragma unroll
    for (int nf = 0; nf < 8; ++nf)
#pragma unroll
      for (int r = 0; r < 4; ++r) {
        const int rl = rg * 32 + mf * 16 + kc * 4 + r;
        const int cl = cg * 128 + nf * 16 + lr;
        stg[rl * 256 + cl] = bf16_rne(acc[mf][nf][r] + bias[nf]);
      }
  __syncthreads();

  unsigned short* dst = (nhalf == 0) ? Pb : Qb;
#pragma unroll
  for (int rep = 0; rep < 8; ++rep) {
    const int i = rep * 256 + t;
    const int row = i >> 5, colu = i & 31;
    if (n0 + row < NNODES)
      *reinterpret_cast<uint4*>(reinterpret_cast<char*>(dst) +
                                (size_t)(n0 + row) * 512 + colu * 16) =
          *reinterpret_cast<const uint4*>(reinterpret_cast<const char*>(stg) +
                                          row * 512 + colu * 16);
  }
}

// ---------------------------------------------------------------------------
// edge_mlp_mfma13: 32-edge tile, 16 KB LDS -> 8 blocks/CU (32 waves, 2x R13).
//   Per wave: 8 edges (16 gather loads, 16 fuses), then wave (wr,wc) computes
//   rows [16wr,+16) x cols [64wc,+64): 8 ds_read_b128 + 32 MFMA.
//   Same per-edge cost as R13; doubled residency for latency hiding.
// ---------------------------------------------------------------------------
__global__ __launch_bounds__(256) void edge_mlp_mfma13(
    const int* __restrict__ ei,
    const unsigned short* __restrict__ W2F, const float* __restrict__ b2,
    const float* __restrict__ W3, const float* __restrict__ b3,
    const unsigned short* __restrict__ Pb, const unsigned short* __restrict__ Qb,
    float* __restrict__ out) {
  const int t  = threadIdx.x;
  const int e0 = blockIdx.x * 32;
  const int wid = t >> 6, lane = t & 63;

  __shared__ __align__(16) unsigned short h1s[32 * 256];  // exactly 16 KB

  // lanes 0-7 hold this wave's 8 edge indices (replicated)
  const int rv = ei[e0 + wid * 8 + (lane & 7)];
  const int cv = ei[NEDGES + e0 + wid * 8 + (lane & 7)];
  const char* Pc = reinterpret_cast<const char*>(Pb);
  const char* Qc = reinterpret_cast<const char*>(Qb);
  const unsigned vo = (unsigned)(lane * 8);   // this lane's 8B of a 512B row

  // ---- gather: 8 edges, 16 uint2 wave-loads ----
  uint2 P[8], Q[8];
#pragma unroll
  for (int j = 0; j < 8; ++j) {
    const int r = __builtin_amdgcn_readlane(rv, j);
    const int c = __builtin_amdgcn_readlane(cv, j);
    P[j] = *reinterpret_cast<const uint2*>(Pc + (size_t)r * 512 + vo);
    Q[j] = *reinterpret_cast<const uint2*>(Qc + (size_t)c * 512 + vo);
  }

#pragma unroll
  for (int j = 0; j < 8; ++j) {
    const int e = wid * 8 + j;                 // e & 7 == j
    const unsigned bt = (unsigned)(e * 512) + (vo ^ ((unsigned)j << 4));
    *reinterpret_cast<uint2*>(reinterpret_cast<char*>(h1s) + bt) =
        make_uint2(fuse2(P[j].x, Q[j].x), fuse2(P[j].y, Q[j].y));
  }
  __syncthreads();

  // ---- MFMA: wave (wr,wc) -> rows [16wr,+16) (1 mf), cols [64wc,+64) (4 nf)
  const int wr = wid >> 1, wc = wid & 1;
  const int lr = lane & 15, kc = lane >> 4;
  const int row = wr * 16 + lr;

  floatx4 acc[4];
#pragma unroll
  for (int nf = 0; nf < 4; ++nf) acc[nf] = (floatx4)0.f;

#pragma unroll
  for (int ks = 0; ks < 8; ++ks) {
    const unsigned bt = (unsigned)(row * 512) +
                        (((unsigned)(ks * 64 + kc * 16)) ^ (((unsigned)(row & 7)) << 4));
    const short8 ah = *reinterpret_cast<const short8*>(
        reinterpret_cast<const char*>(h1s) + bt);
    short8 bh[4];
#pragma unroll
    for (int nf = 0; nf < 4; ++nf) {
      const unsigned off = (unsigned)(((ks * 8 + wc * 4 + nf) * 64 + lane) * 8);
      bh[nf] = *reinterpret_cast<const short8*>(W2F + off);
    }
#pragma unroll
    for (int nf = 0; nf < 4; ++nf)
      acc[nf] = __builtin_amdgcn_mfma_f32_16x16x32_bf16(ah, bh[nf], acc[nf], 0, 0, 0);
  }

  // ---- epilogue: leaky_relu(C+b2) @ W3, reduce over 16 col-lanes ----
  float w3v[4], b2v[4];
#pragma unroll
  for (int nf = 0; nf < 4; ++nf) {
    const int col = wc * 64 + nf * 16 + lr;
    w3v[nf] = W3[col];
    b2v[nf] = b2[col];
  }

  float part[4];
#pragma unroll
  for (int r = 0; r < 4; ++r) {
    float s = 0.f;
#pragma unroll
    for (int nf = 0; nf < 4; ++nf) {
      float h = acc[nf][r] + b2v[nf];
      h = (h > 0.f) ? h : LEAKY * h;
      s = fmaf(h, w3v[nf], s);
    }
    part[r] = s;
  }

#pragma unroll
  for (int m = 1; m <= 8; m <<= 1)
#pragma unroll
    for (int r = 0; r < 4; ++r) part[r] += __shfl_xor(part[r], m, 64);

  // ---- outs aliased into h1s (all h1s MFMA reads complete) ----
  __syncthreads();
  float* outs = reinterpret_cast<float*>(h1s);   // 4 waves x 16 floats = 256 B

  if (lr == 0) {
#pragma unroll
    for (int r = 0; r < 4; ++r) outs[wid * 16 + kc * 4 + r] = part[r];
  }
  __syncthreads();

  if (t < 32) {
    const int wrg = t >> 4;   // row-group
    out[e0 + t] = outs[(wrg * 2) * 16 + (t & 15)] +
                  outs[(wrg * 2 + 1) * 16 + (t & 15)] + b3[0];
  }
}

// ---------------------------------------------------------------------------
// Fallback (ws too small): direct fp32 path, 32-edge tiles.
// ---------------------------------------------------------------------------
__global__ __launch_bounds__(256) void edge_mlp_direct(
    const float* __restrict__ x, const int* __restrict__ ei,
    const float* __restrict__ W1, const float* __restrict__ b1,
    const float* __restrict__ W2, const float* __restrict__ b2,
    const float* __restrict__ W3, const float* __restrict__ b3,
    float* __restrict__ out) {
  const int t  = threadIdx.x;
  const int e0 = blockIdx.x * 32;

  __shared__ __align__(16) float h1f[32 * HID];
  __shared__ int eidx[2][32];

  if (t < 32)      eidx[0][t]      = ei[e0 + t];
  else if (t < 64) eidx[1][t - 32] = ei[NEDGES + e0 + (t - 32)];
  __syncthreads();

  const float b1r = b1[t];
  __shared__ float xr[32][128];
  __shared__ float xc[32][128];
  for (int idx = t; idx < 32 * 128; idx += 256) {
    const int e = idx >> 7, f = idx & 127;
    xr[e][f] = x[(size_t)eidx[0][e] * NFEAT + f];
    xc[e][f] = x[(size_t)eidx[1][e] * NFEAT + f];
  }
  __syncthreads();
  float s[32];
#pragma unroll
  for (int e = 0; e < 32; ++e) s[e] = b1r;
  for (int f = 0; f < 128; ++f) {
    const float wr = W1[f * HID + t];
    const float wb = W1[(128 + f) * HID + t];
#pragma unroll
    for (int e = 0; e < 32; ++e)
      s[e] = fmaf(xr[e][f], wr, fmaf(xc[e][f], wb, s[e]));
  }
#pragma unroll
  for (int e = 0; e < 32; ++e) h1f[e * HID + t] = fmaxf(s[e], 0.f);
  __syncthreads();

  const int tr = t >> 5;
  const int tc = t & 31;
  float acc[4][4];
#pragma unroll
  for (int i = 0; i < 4; ++i)
#pragma unroll
    for (int j = 0; j < 4; ++j) acc[i][j] = 0.f;

  const float4* __restrict__ W2v = reinterpret_cast<const float4*>(W2);
  const float4* __restrict__ h1v = reinterpret_cast<const float4*>(h1f);
  for (int k = 0; k < HID; k += 4) {
    float4 a[4];
#pragma unroll
    for (int i = 0; i < 4; ++i) a[i] = h1v[((4 * tr + i) * HID + k) >> 2];
    float4 b[4];
#pragma unroll
    for (int kk = 0; kk < 4; ++kk) b[kk] = W2v[(k + kk) * 32 + tc];
#pragma unroll
    for (int i = 0; i < 4; ++i) {
      const float* av = reinterpret_cast<const float*>(&a[i]);
#pragma unroll
      for (int kk = 0; kk < 4; ++kk) {
        const float* bv = reinterpret_cast<const float*>(&b[kk]);
#pragma unroll
        for (int j = 0; j < 4; ++j) acc[i][j] = fmaf(av[kk], bv[j], acc[i][j]);
      }
    }
  }

  float w3r[4], b2r[4];
#pragma unroll
  for (int j = 0; j < 4; ++j) {
    w3r[j] = W3[4 * tc + j];
    b2r[j] = b2[4 * tc + j];
  }
  const float b3v = b3[0];
  float partial[4];
#pragma unroll
  for (int i = 0; i < 4; ++i) {
    float sp = 0.f;
#pragma unroll
    for (int j = 0; j < 4; ++j) {
      float h = acc[i][j] + b2r[j];
      h = (h > 0.f) ? h : LEAKY * h;
      sp = fmaf(h, w3r[j], sp);
    }
    partial[i] = sp;
  }
#pragma unroll
  for (int m = 16; m >= 1; m >>= 1)
#pragma unroll
    for (int i = 0; i < 4; ++i) partial[i] += __shfl_xor(partial[i], m, 32);
  if (tc == 0) {
#pragma unroll
    for (int i = 0; i < 4; ++i) out[e0 + 4 * tr + i] = partial[i] + b3v;
  }
}

extern "C" void kernel_launch(void* const* d_in, const int* in_sizes, int n_in,
                              void* d_out, int out_size, void* d_ws, size_t ws_size,
                              hipStream_t stream) {
  const float* x  = (const float*)d_in[0];
  const int*   ei = (const int*)d_in[1];
  const float* W1 = (const float*)d_in[2];
  const float* b1 = (const float*)d_in[3];
  const float* W2 = (const float*)d_in[4];
  const float* b2 = (const float*)d_in[5];
  const float* W3 = (const float*)d_in[6];
  const float* b3 = (const float*)d_in[7];
  float* out = (float*)d_out;

  const size_t p_bytes   = (size_t)NNODES * 256 * 2;      // 25,600,000
  const size_t w2f_bytes = (size_t)32768 * 2;             // 65,536
  const size_t w1f_bytes = (size_t)2 * 65536 * 2;         // 262,144
  const size_t need = 2 * p_bytes + w2f_bytes + w1f_bytes;

  if (ws_size >= need) {
    unsigned short* Pb  = (unsigned short*)d_ws;
    unsigned short* Qb  = (unsigned short*)((char*)d_ws + p_bytes);
    unsigned short* W2F = (unsigned short*)((char*)d_ws + 2 * p_bytes);
    unsigned short* W1F = (unsigned short*)((char*)d_ws + 2 * p_bytes + w2f_bytes);

    pack_w<<<(32768 + 65536 + 255) / 256, 256, 0, stream>>>(W2, W1, W2F, W1F);
    const int pq_blocks = ((NNODES + 63) / 64) * 2;       // 1564
    pq_mfma<<<pq_blocks, 256, 0, stream>>>(x, W1F, b1, Pb, Qb);
    edge_mlp_mfma13<<<NEDGES / 32, 256, 0, stream>>>(ei, W2F, b2, W3, b3, Pb, Qb, out);
  } else {
    edge_mlp_direct<<<NEDGES / 32, 256, 0, stream>>>(x, ei, W1, b1, W2, b2, W3, b3, out);
  }
}

// Round 15
// 146.162 us; speedup vs baseline: 1.1393x; 1.1393x over previous
//
#include <hip/hip_runtime.h>
#include <hip/hip_bf16.h>

#define NNODES 50000
#define NFEAT  128
#define NEDGES 600000
#define HID    256
#define HID2   128
#define LEAKY  0.01f

typedef __attribute__((ext_vector_type(8))) short short8;
typedef __attribute__((ext_vector_type(4))) float floatx4;

__device__ __forceinline__ void split_bf16(float x, unsigned short& hi, unsigned short& lo) {
  union { float f; unsigned u; } a; a.f = x;
  hi = (unsigned short)(a.u >> 16);
  union { float f; unsigned u; } h; h.u = (unsigned)hi << 16;
  union { float f; unsigned u; } r; r.f = x - h.f;
  lo = (unsigned short)(r.u >> 16);
}

__device__ __forceinline__ unsigned short bf16_rne(float x) {
  union { float f; unsigned u; } a; a.f = x;
  unsigned r = a.u + 0x7FFFu + ((a.u >> 16) & 1u);
  return (unsigned short)(r >> 16);
}

// RNE pack two fp32 -> u32 of 2 bf16 (a in low half) — emits cvt_pk.
__device__ __forceinline__ unsigned pack2_rne(float a, float b) {
  __hip_bfloat162 h = __float22bfloat162_rn(make_float2(a, b));
  unsigned u; __builtin_memcpy(&u, &h, 4); return u;
}

__device__ __forceinline__ float ubits2f(unsigned u) {
  union { unsigned u; float f; } c; c.u = u; return c.f;
}

// relu(P+Q) for a packed bf16 pair (b1 pre-folded into P), repacked RNE.
__device__ __forceinline__ unsigned fuse2(unsigned pw, unsigned qw) {
  const float a0 = ubits2f(pw << 16), a1 = ubits2f(pw & 0xFFFF0000u);
  const float c0 = ubits2f(qw << 16), c1 = ubits2f(qw & 0xFFFF0000u);
  return pack2_rne(fmaxf(a0 + c0, 0.f), fmaxf(a1 + c1, 0.f));
}

// ---------------------------------------------------------------------------
// pack_w: W2 -> single-plane RNE bf16 B-frag order; W1' -> hi/lo split planes.
// W2F[((ks*8+nf)*64+l)*8+i]:  k=ks*32+(l>>4)*8+i, col=nf*16+(l&15)
// W1F[((ks*32+nf)*64+l)*8+i]: k=ks*32+(l>>4)*8+i, n=nf*16+(l&15)
//   W1'[k][n] = n<256 ? W1[k][n] : W1[128+k][n-256]
// ---------------------------------------------------------------------------
__global__ __launch_bounds__(256) void pack_w(const float* __restrict__ W2,
                                              const float* __restrict__ W1,
                                              unsigned short* __restrict__ W2F,
                                              unsigned short* __restrict__ W1F) {
  const int gid = blockIdx.x * 256 + threadIdx.x;
  if (gid < 32768) {
    const int idx = gid;
    const int i  = idx & 7;
    const int l  = (idx >> 3) & 63;
    const int nf = (idx >> 9) & 7;
    const int ks = idx >> 12;
    const int k   = ks * 32 + (l >> 4) * 8 + i;
    const int col = nf * 16 + (l & 15);
    W2F[idx] = bf16_rne(W2[k * HID2 + col]);
  } else if (gid < 32768 + 65536) {
    const int idx = gid - 32768;
    const int i  = idx & 7;
    const int l  = (idx >> 3) & 63;
    const int nf = (idx >> 9) & 31;
    const int ks = idx >> 14;
    const int k = ks * 32 + (l >> 4) * 8 + i;
    const int n = nf * 16 + (l & 15);
    const float v = (n < 256) ? W1[k * HID + n] : W1[(128 + k) * HID + (n - 256)];
    unsigned short hi, lo;
    split_bf16(v, hi, lo);
    W1F[idx]         = hi;
    W1F[65536 + idx] = lo;
  }
}

// ---------------------------------------------------------------------------
// pq_mfma (2-term): Pb[n][0:256] = bf16_rne( xb[n] @ W1'[:,0:256] + b1 )
//                   Qb[n][0:256] = bf16_rne( xb[n] @ W1'[:,256:512] )
// where xb = RNE-bf16(x). 2-term split (Ah*Bh + Ah*Bl) keeps FULL W1
// precision; x-rounding error (~2^-9 rel) matches the PQ storage RNE that
// was already present -> absmax grows only ~sqrt(2)x, far under threshold.
// x staged as a single 16 KB plane; 32 KB stg overlays the same buffer.
// ---------------------------------------------------------------------------
__global__ __launch_bounds__(256) void pq_mfma(
    const float* __restrict__ x, const unsigned short* __restrict__ W1F,
    const float* __restrict__ b1,
    unsigned short* __restrict__ Pb, unsigned short* __restrict__ Qb) {
  const int bid   = blockIdx.x;
  const int nhalf = bid & 1;
  const int n0    = (bid >> 1) * 64;
  const int t     = threadIdx.x;

  __shared__ __align__(16) unsigned short sbuf[64 * 256];  // 32 KB
  unsigned short* xhi = sbuf;   // first 16 KB: x tile [64][128] bf16, swizzled

  // stage x tile -> RNE bf16 single plane
#pragma unroll
  for (int rep = 0; rep < 8; ++rep) {
    const int flat = rep * 1024 + t * 4;
    const int row = flat >> 7, f0 = flat & 127;
    float4 v = make_float4(0.f, 0.f, 0.f, 0.f);
    if (n0 + row < NNODES)
      v = *reinterpret_cast<const float4*>(&x[(size_t)(n0 + row) * NFEAT + f0]);
    const unsigned bt = (unsigned)(row * 256) +
                        (((unsigned)(2 * f0)) ^ (((unsigned)(row & 7)) << 4));
    *reinterpret_cast<uint2*>(reinterpret_cast<char*>(xhi) + bt) =
        make_uint2(pack2_rne(v.x, v.y), pack2_rne(v.z, v.w));
  }
  __syncthreads();

  const int wid = t >> 6, lane = t & 63;
  const int rg = wid >> 1, cg = wid & 1;
  const int lr = lane & 15, kc = lane >> 4;

  floatx4 acc[2][8];
#pragma unroll
  for (int mf = 0; mf < 2; ++mf)
#pragma unroll
    for (int nf = 0; nf < 8; ++nf) acc[mf][nf] = (floatx4)0.f;

#pragma unroll
  for (int ks = 0; ks < 4; ++ks) {
    short8 ah[2];
#pragma unroll
    for (int mf = 0; mf < 2; ++mf) {
      const int row = rg * 32 + mf * 16 + lr;
      const unsigned bt = (unsigned)(row * 256) +
                          (((unsigned)(ks * 64 + kc * 16)) ^ (((unsigned)(row & 7)) << 4));
      ah[mf] = *reinterpret_cast<const short8*>(reinterpret_cast<const char*>(xhi) + bt);
    }
#pragma unroll
    for (int nf = 0; nf < 8; ++nf) {
      const int nfg = nhalf * 16 + cg * 8 + nf;
      const size_t off = ((size_t)(ks * 32 + nfg) * 64 + lane) * 8;
      const short8 bh = *reinterpret_cast<const short8*>(W1F + off);
      const short8 bl = *reinterpret_cast<const short8*>(W1F + 65536 + off);
#pragma unroll
      for (int mf = 0; mf < 2; ++mf) {
        acc[mf][nf] = __builtin_amdgcn_mfma_f32_16x16x32_bf16(ah[mf], bh, acc[mf][nf], 0, 0, 0);
        acc[mf][nf] = __builtin_amdgcn_mfma_f32_16x16x32_bf16(ah[mf], bl, acc[mf][nf], 0, 0, 0);
      }
    }
  }

  float bias[8];
#pragma unroll
  for (int nf = 0; nf < 8; ++nf)
    bias[nf] = (nhalf == 0) ? b1[cg * 128 + nf * 16 + lr] : 0.f;

  __syncthreads();  // xhi reads done before reuse as 32 KB staging
  unsigned short* stg = sbuf;
#pragma unroll
  for (int mf = 0; mf < 2; ++mf)
#pragma unroll
    for (int nf = 0; nf < 8; ++nf)
#pragma unroll
      for (int r = 0; r < 4; ++r) {
        const int rl = rg * 32 + mf * 16 + kc * 4 + r;
        const int cl = cg * 128 + nf * 16 + lr;
        stg[rl * 256 + cl] = bf16_rne(acc[mf][nf][r] + bias[nf]);
      }
  __syncthreads();

  unsigned short* dst = (nhalf == 0) ? Pb : Qb;
#pragma unroll
  for (int rep = 0; rep < 8; ++rep) {
    const int i = rep * 256 + t;
    const int row = i >> 5, colu = i & 31;
    if (n0 + row < NNODES)
      *reinterpret_cast<uint4*>(reinterpret_cast<char*>(dst) +
                                (size_t)(n0 + row) * 512 + colu * 16) =
          *reinterpret_cast<const uint4*>(reinterpret_cast<const char*>(stg) +
                                          row * 512 + colu * 16);
  }
}

// ---------------------------------------------------------------------------
// edge_mlp_mfma12 (R13-proven best): 64-edge tile, 2x2 wave split, 32 KB LDS,
// outs aliased into h1s. gather: readlane -> SGPR-base uint2; single-plane W2.
// ---------------------------------------------------------------------------
__global__ __launch_bounds__(256) void edge_mlp_mfma12(
    const int* __restrict__ ei,
    const unsigned short* __restrict__ W2F, const float* __restrict__ b2,
    const float* __restrict__ W3, const float* __restrict__ b3,
    const unsigned short* __restrict__ Pb, const unsigned short* __restrict__ Qb,
    float* __restrict__ out) {
  const int t  = threadIdx.x;
  const int e0 = blockIdx.x * 64;
  const int wid = t >> 6, lane = t & 63;

  __shared__ __align__(16) unsigned short h1s[64 * 256];  // exactly 32 KB

  const int rv = ei[e0 + wid * 16 + (lane & 15)];
  const int cv = ei[NEDGES + e0 + wid * 16 + (lane & 15)];
  const char* Pc = reinterpret_cast<const char*>(Pb);
  const char* Qc = reinterpret_cast<const char*>(Qb);
  const unsigned vo = (unsigned)(lane * 8);

  uint2 P0[8], Q0[8], P1[8], Q1[8];
#pragma unroll
  for (int j = 0; j < 8; ++j) {
    const int r = __builtin_amdgcn_readlane(rv, j);
    const int c = __builtin_amdgcn_readlane(cv, j);
    P0[j] = *reinterpret_cast<const uint2*>(Pc + (size_t)r * 512 + vo);
    Q0[j] = *reinterpret_cast<const uint2*>(Qc + (size_t)c * 512 + vo);
  }
#pragma unroll
  for (int j = 0; j < 8; ++j) {
    const int r = __builtin_amdgcn_readlane(rv, 8 + j);
    const int c = __builtin_amdgcn_readlane(cv, 8 + j);
    P1[j] = *reinterpret_cast<const uint2*>(Pc + (size_t)r * 512 + vo);
    Q1[j] = *reinterpret_cast<const uint2*>(Qc + (size_t)c * 512 + vo);
  }

#pragma unroll
  for (int j = 0; j < 8; ++j) {
    const int e = wid * 16 + j;
    const unsigned bt = (unsigned)(e * 512) + (vo ^ (((unsigned)(e & 7)) << 4));
    *reinterpret_cast<uint2*>(reinterpret_cast<char*>(h1s) + bt) =
        make_uint2(fuse2(P0[j].x, Q0[j].x), fuse2(P0[j].y, Q0[j].y));
  }
#pragma unroll
  for (int j = 0; j < 8; ++j) {
    const int e = wid * 16 + 8 + j;
    const unsigned bt = (unsigned)(e * 512) + (vo ^ (((unsigned)(e & 7)) << 4));
    *reinterpret_cast<uint2*>(reinterpret_cast<char*>(h1s) + bt) =
        make_uint2(fuse2(P1[j].x, Q1[j].x), fuse2(P1[j].y, Q1[j].y));
  }
  __syncthreads();

  // ---- MFMA: wave (wr,wc) -> rows [32wr,+32) (2 mf), cols [64wc,+64) (4 nf)
  const int wr = wid >> 1, wc = wid & 1;
  const int lr = lane & 15, kc = lane >> 4;

  floatx4 acc[2][4];
#pragma unroll
  for (int mf = 0; mf < 2; ++mf)
#pragma unroll
    for (int nf = 0; nf < 4; ++nf) acc[mf][nf] = (floatx4)0.f;

#pragma unroll
  for (int ks = 0; ks < 8; ++ks) {
    short8 ah[2];
#pragma unroll
    for (int mf = 0; mf < 2; ++mf) {
      const int row = wr * 32 + mf * 16 + lr;
      const unsigned bt = (unsigned)(row * 512) +
                          (((unsigned)(ks * 64 + kc * 16)) ^ (((unsigned)(row & 7)) << 4));
      ah[mf] = *reinterpret_cast<const short8*>(reinterpret_cast<const char*>(h1s) + bt);
    }
    short8 bh[4];
#pragma unroll
    for (int nf = 0; nf < 4; ++nf) {
      const unsigned off = (unsigned)(((ks * 8 + wc * 4 + nf) * 64 + lane) * 8);
      bh[nf] = *reinterpret_cast<const short8*>(W2F + off);
    }
#pragma unroll
    for (int mf = 0; mf < 2; ++mf)
#pragma unroll
      for (int nf = 0; nf < 4; ++nf)
        acc[mf][nf] = __builtin_amdgcn_mfma_f32_16x16x32_bf16(ah[mf], bh[nf], acc[mf][nf], 0, 0, 0);
  }

  // ---- epilogue: leaky_relu(C+b2) @ W3, reduce over 16 col-lanes ----
  float w3v[4], b2v[4];
#pragma unroll
  for (int nf = 0; nf < 4; ++nf) {
    const int col = wc * 64 + nf * 16 + lr;
    w3v[nf] = W3[col];
    b2v[nf] = b2[col];
  }

  float part[2][4];
#pragma unroll
  for (int mf = 0; mf < 2; ++mf)
#pragma unroll
    for (int r = 0; r < 4; ++r) {
      float s = 0.f;
#pragma unroll
      for (int nf = 0; nf < 4; ++nf) {
        float h = acc[mf][nf][r] + b2v[nf];
        h = (h > 0.f) ? h : LEAKY * h;
        s = fmaf(h, w3v[nf], s);
      }
      part[mf][r] = s;
    }

#pragma unroll
  for (int m = 1; m <= 8; m <<= 1)
#pragma unroll
    for (int mf = 0; mf < 2; ++mf)
#pragma unroll
      for (int r = 0; r < 4; ++r) part[mf][r] += __shfl_xor(part[mf][r], m, 64);

  // ---- outs aliased into h1s (all h1s MFMA reads are complete) ----
  __syncthreads();
  float* outs = reinterpret_cast<float*>(h1s);   // 4 waves x 32 floats = 512 B

  if (lr == 0) {
#pragma unroll
    for (int mf = 0; mf < 2; ++mf)
#pragma unroll
      for (int r = 0; r < 4; ++r) outs[wid * 32 + mf * 16 + kc * 4 + r] = part[mf][r];
  }
  __syncthreads();

  if (t < 64) {
    const int wrg = t >> 5;
    out[e0 + t] = outs[(wrg * 2) * 32 + (t & 31)] +
                  outs[(wrg * 2 + 1) * 32 + (t & 31)] + b3[0];
  }
}

// ---------------------------------------------------------------------------
// Fallback (ws too small): direct fp32 path, 32-edge tiles.
// ---------------------------------------------------------------------------
__global__ __launch_bounds__(256) void edge_mlp_direct(
    const float* __restrict__ x, const int* __restrict__ ei,
    const float* __restrict__ W1, const float* __restrict__ b1,
    const float* __restrict__ W2, const float* __restrict__ b2,
    const float* __restrict__ W3, const float* __restrict__ b3,
    float* __restrict__ out) {
  const int t  = threadIdx.x;
  const int e0 = blockIdx.x * 32;

  __shared__ __align__(16) float h1f[32 * HID];
  __shared__ int eidx[2][32];

  if (t < 32)      eidx[0][t]      = ei[e0 + t];
  else if (t < 64) eidx[1][t - 32] = ei[NEDGES + e0 + (t - 32)];
  __syncthreads();

  const float b1r = b1[t];
  __shared__ float xr[32][128];
  __shared__ float xc[32][128];
  for (int idx = t; idx < 32 * 128; idx += 256) {
    const int e = idx >> 7, f = idx & 127;
    xr[e][f] = x[(size_t)eidx[0][e] * NFEAT + f];
    xc[e][f] = x[(size_t)eidx[1][e] * NFEAT + f];
  }
  __syncthreads();
  float s[32];
#pragma unroll
  for (int e = 0; e < 32; ++e) s[e] = b1r;
  for (int f = 0; f < 128; ++f) {
    const float wr = W1[f * HID + t];
    const float wb = W1[(128 + f) * HID + t];
#pragma unroll
    for (int e = 0; e < 32; ++e)
      s[e] = fmaf(xr[e][f], wr, fmaf(xc[e][f], wb, s[e]));
  }
#pragma unroll
  for (int e = 0; e < 32; ++e) h1f[e * HID + t] = fmaxf(s[e], 0.f);
  __syncthreads();

  const int tr = t >> 5;
  const int tc = t & 31;
  float acc[4][4];
#pragma unroll
  for (int i = 0; i < 4; ++i)
#pragma unroll
    for (int j = 0; j < 4; ++j) acc[i][j] = 0.f;

  const float4* __restrict__ W2v = reinterpret_cast<const float4*>(W2);
  const float4* __restrict__ h1v = reinterpret_cast<const float4*>(h1f);
  for (int k = 0; k < HID; k += 4) {
    float4 a[4];
#pragma unroll
    for (int i = 0; i < 4; ++i) a[i] = h1v[((4 * tr + i) * HID + k) >> 2];
    float4 b[4];
#pragma unroll
    for (int kk = 0; kk < 4; ++kk) b[kk] = W2v[(k + kk) * 32 + tc];
#pragma unroll
    for (int i = 0; i < 4; ++i) {
      const float* av = reinterpret_cast<const float*>(&a[i]);
#pragma unroll
      for (int kk = 0; kk < 4; ++kk) {
        const float* bv = reinterpret_cast<const float*>(&b[kk]);
#pragma unroll
        for (int j = 0; j < 4; ++j) acc[i][j] = fmaf(av[kk], bv[j], acc[i][j]);
      }
    }
  }

  float w3r[4], b2r[4];
#pragma unroll
  for (int j = 0; j < 4; ++j) {
    w3r[j] = W3[4 * tc + j];
    b2r[j] = b2[4 * tc + j];
  }
  const float b3v = b3[0];
  float partial[4];
#pragma unroll
  for (int i = 0; i < 4; ++i) {
    float sp = 0.f;
#pragma unroll
    for (int j = 0; j < 4; ++j) {
      float h = acc[i][j] + b2r[j];
      h = (h > 0.f) ? h : LEAKY * h;
      sp = fmaf(h, w3r[j], sp);
    }
    partial[i] = sp;
  }
#pragma unroll
  for (int m = 16; m >= 1; m >>= 1)
#pragma unroll
    for (int i = 0; i < 4; ++i) partial[i] += __shfl_xor(partial[i], m, 32);
  if (tc == 0) {
#pragma unroll
    for (int i = 0; i < 4; ++i) out[e0 + 4 * tr + i] = partial[i] + b3v;
  }
}

extern "C" void kernel_launch(void* const* d_in, const int* in_sizes, int n_in,
                              void* d_out, int out_size, void* d_ws, size_t ws_size,
                              hipStream_t stream) {
  const float* x  = (const float*)d_in[0];
  const int*   ei = (const int*)d_in[1];
  const float* W1 = (const float*)d_in[2];
  const float* b1 = (const float*)d_in[3];
  const float* W2 = (const float*)d_in[4];
  const float* b2 = (const float*)d_in[5];
  const float* W3 = (const float*)d_in[6];
  const float* b3 = (const float*)d_in[7];
  float* out = (float*)d_out;

  const size_t p_bytes   = (size_t)NNODES * 256 * 2;      // 25,600,000
  const size_t w2f_bytes = (size_t)32768 * 2;             // 65,536
  const size_t w1f_bytes = (size_t)2 * 65536 * 2;         // 262,144
  const size_t need = 2 * p_bytes + w2f_bytes + w1f_bytes;

  if (ws_size >= need) {
    unsigned short* Pb  = (unsigned short*)d_ws;
    unsigned short* Qb  = (unsigned short*)((char*)d_ws + p_bytes);
    unsigned short* W2F = (unsigned short*)((char*)d_ws + 2 * p_bytes);
    unsigned short* W1F = (unsigned short*)((char*)d_ws + 2 * p_bytes + w2f_bytes);

    pack_w<<<(32768 + 65536 + 255) / 256, 256, 0, stream>>>(W2, W1, W2F, W1F);
    const int pq_blocks = ((NNODES + 63) / 64) * 2;       // 1564
    pq_mfma<<<pq_blocks, 256, 0, stream>>>(x, W1F, b1, Pb, Qb);
    edge_mlp_mfma12<<<NEDGES / 64, 256, 0, stream>>>(ei, W2F, b2, W3, b3, Pb, Qb, out);
  } else {
    edge_mlp_direct<<<NEDGES / 32, 256, 0, stream>>>(x, ei, W1, b1, W2, b2, W3, b3, out);
  }
}